// Round 11
// baseline (65.268 us; speedup 1.0000x reference)
//
#include <hip/hip_runtime.h>

#define NBINS 256
#define NBUCK 4096            // 2^12 bit-space buckets (sign+exp+3 mantissa bits)
#define BSHIFT 20             // f2o(x) >> 20 -> bucket index
#define P1BLK 2048            // pass1 blocks: 8/CU (16.4 KB LDS each), 32 waves/CU
#define NCPY 2                // LDS histogram copies (selected by lane&1)
#define CSTRIDE 2049          // words; 2049 % 32 == 1 -> copies offset by one bank

// ws layout (uint32 word offsets):
//   [0 .. 2*P1BLK)   per-block ordered min/max pairs (u[2b], u[2b+1])
//   HOFF_W           P1BLK x NBUCK partial hists, PACKED USHORT (NBUCK/2 words/row)
//   FOFF_W           final NBUCK histogram (u32)
#define HOFF_W 4096u
#define FOFF_W (HOFF_W + (unsigned)P1BLK * (NBUCK / 2))   // 4,198,400

__device__ __forceinline__ unsigned int f2o(float f) {
    unsigned int u = __float_as_uint(f);
    return (u & 0x80000000u) ? ~u : (u | 0x80000000u);
}
__device__ __forceinline__ float o2f(unsigned int u) {
    unsigned int v = (u & 0x80000000u) ? (u & 0x7fffffffu) : ~u;
    return __uint_as_float(v);
}
__device__ __forceinline__ unsigned int umn(unsigned int a, unsigned int b) { return a < b ? a : b; }
__device__ __forceinline__ unsigned int umx(unsigned int a, unsigned int b) { return a > b ? a : b; }

// n16 = n/16; each thread consumes four contiguous float4 (64 B) per iteration.
// LDS: 2 histogram copies (lane&1), u16 counters packed in u32 words
// (bucket k -> word k>>1, half k&1). Per-block per-bucket count <= n/P1BLK =
// 32768, so low-half adds never carry into the high half, and the dump-time
// packed sum of the two copies stays < 65536 per bucket.
__global__ void __launch_bounds__(256) hrt_pass1(const float4* __restrict__ in, int n16,
                                                 unsigned int* __restrict__ wsu) {
    __shared__ unsigned int h[NCPY * CSTRIDE];
    for (int i = threadIdx.x; i < NCPY * CSTRIDE; i += 256) h[i] = 0u;
    __syncthreads();
    unsigned int mnu = 0xFFFFFFFFu, mxu = 0u;
    unsigned int cbase = (threadIdx.x & 1u) * CSTRIDE;

#define PROC4(v) { \
    unsigned int u0 = f2o(v.x), u1 = f2o(v.y), u2 = f2o(v.z), u3 = f2o(v.w); \
    mnu = umn(mnu, umn(umn(u0, u1), umn(u2, u3))); \
    mxu = umx(mxu, umx(umx(u0, u1), umx(u2, u3))); \
    unsigned int k0 = u0 >> BSHIFT, k1 = u1 >> BSHIFT, k2 = u2 >> BSHIFT, k3 = u3 >> BSHIFT; \
    atomicAdd(&h[cbase + (k0 >> 1)], (k0 & 1u) ? 0x10000u : 1u); \
    atomicAdd(&h[cbase + (k1 >> 1)], (k1 & 1u) ? 0x10000u : 1u); \
    atomicAdd(&h[cbase + (k2 >> 1)], (k2 & 1u) ? 0x10000u : 1u); \
    atomicAdd(&h[cbase + (k3 >> 1)], (k3 & 1u) ? 0x10000u : 1u); }

    int stride = P1BLK * 256;
    for (int i = blockIdx.x * 256 + threadIdx.x; i < n16; i += stride) {
        float4 v0 = in[4 * i];
        float4 v1 = in[4 * i + 1];
        float4 v2 = in[4 * i + 2];
        float4 v3 = in[4 * i + 3];
        PROC4(v0); PROC4(v1); PROC4(v2); PROC4(v3);
    }
#undef PROC4

    #pragma unroll
    for (int off = 32; off > 0; off >>= 1) {
        mnu = umn(mnu, (unsigned int)__shfl_down((int)mnu, off));
        mxu = umx(mxu, (unsigned int)__shfl_down((int)mxu, off));
    }
    __shared__ unsigned int smn[4], smx[4];
    int lane = threadIdx.x & 63, wid = threadIdx.x >> 6;
    if (lane == 0) { smn[wid] = mnu; smx[wid] = mxu; }
    __syncthreads();
    if (threadIdx.x == 0) {
        #pragma unroll
        for (int w = 1; w < 4; ++w) { mnu = umn(mnu, smn[w]); mxu = umx(mxu, smx[w]); }
        wsu[2 * blockIdx.x]     = mnu;
        wsu[2 * blockIdx.x + 1] = mxu;
    }
    __syncthreads();
    // dump: sum the two copies; rows stay in the packed-ushort format
    unsigned int* row = wsu + HOFF_W + (unsigned)blockIdx.x * (NBUCK / 2);
    for (int k = threadIdx.x; k < NBUCK / 2; k += 256)
        row[k] = h[k] + h[CSTRIDE + k];
}

// Single merged reduce: 256 blocks; block b owns 8 packed words (16 buckets).
// Thread t: word wl = t&7, row-group r0 = t>>3 (32 groups, stride 32 over 2048
// rows -> 64 rows/thread). LDS tree collapses the 32 row-groups; 8 threads
// write the 16 final u32 buckets. Replaces reduceA+reduceB and the 1 MB
// intermediate round-trip.
__global__ void __launch_bounds__(256) hrt_reduce(unsigned int* __restrict__ wsu) {
    __shared__ unsigned int slo[256], shi[256];
    int t = threadIdx.x;
    int wl = t & 7;
    int r0 = t >> 3;
    unsigned int w = (unsigned)blockIdx.x * 8 + wl;
    const unsigned int* src = wsu + HOFF_W + w;
    unsigned int lo = 0, hi = 0;
    for (int r = r0; r < P1BLK; r += 32) {
        unsigned int v = src[(unsigned)r * (NBUCK / 2)];
        lo += v & 0xFFFFu;
        hi += v >> 16;
    }
    slo[t] = lo; shi[t] = hi;
    __syncthreads();
    #pragma unroll
    for (int off = 128; off >= 8; off >>= 1) {
        if (t < off) { slo[t] += slo[t + off]; shi[t] += shi[t + off]; }
        __syncthreads();
    }
    if (t < 8) {
        unsigned int ww = (unsigned)blockIdx.x * 8 + t;
        wsu[FOFF_W + 2 * ww]     = slo[t];   // even bucket of word ww
        wsu[FOFF_W + 2 * ww + 1] = shi[t];   // odd bucket
    }
}

__global__ void __launch_bounds__(1024) hrt_finalize(const unsigned int* __restrict__ wsu,
                                                     float* __restrict__ out) {
    __shared__ unsigned int excl[NBUCK + 1];
    __shared__ unsigned int ssum[1024];
    __shared__ unsigned int redmn[16], redmx[16];
    __shared__ float sm[2];
    int t = threadIdx.x;

    unsigned int mnu = 0xFFFFFFFFu, mxu = 0u;
    for (int i = t; i < P1BLK; i += 1024) {
        mnu = umn(mnu, wsu[2 * i]);
        mxu = umx(mxu, wsu[2 * i + 1]);
    }
    #pragma unroll
    for (int off = 32; off > 0; off >>= 1) {
        mnu = umn(mnu, (unsigned int)__shfl_down((int)mnu, off));
        mxu = umx(mxu, (unsigned int)__shfl_down((int)mxu, off));
    }
    int lane = t & 63, wid = t >> 6;
    if (lane == 0) { redmn[wid] = mnu; redmx[wid] = mxu; }

    // 4 buckets per thread
    const uint4* fh = (const uint4*)(wsu + FOFF_W);
    uint4 a = fh[t];
    unsigned int c[4] = { a.x, a.y, a.z, a.w };
    unsigned int s4 = c[0] + c[1] + c[2] + c[3];
    ssum[t] = s4;
    __syncthreads();

    for (int off = 1; off < 1024; off <<= 1) {
        unsigned int v = ssum[t];
        if (t >= off) v += ssum[t - off];
        __syncthreads();
        ssum[t] = v;
        __syncthreads();
    }
    unsigned int run = ssum[t] - s4;
    #pragma unroll
    for (int j = 0; j < 4; ++j) { excl[4 * t + j] = run; run += c[j]; }
    if (t == 1023) excl[NBUCK] = run;

    if (t == 0) {
        unsigned int m1 = 0xFFFFFFFFu, m2 = 0u;
        #pragma unroll
        for (int w = 0; w < 16; ++w) { m1 = umn(m1, redmn[w]); m2 = umx(m2, redmx[w]); }
        sm[0] = o2f(m1); sm[1] = o2f(m2);
    }
    __syncthreads();

    if (t < NBINS) {
        double mn = (double)sm[0], mx = (double)sm[1];
        unsigned int total = excl[NBUCK];
        double delta = (mx - mn) / (double)NBINS;
        double thr0 = (double)total * ((1.0 - 0.99) / 2.0);
        double thr1 = (double)total * ((1.0 + 0.99) / 2.0);

        auto estcum = [&](double e) -> double {
            unsigned int u = f2o((float)e);
            unsigned int k = u >> BSHIFT;
            unsigned int lou = k << BSHIFT;
            unsigned int hiu = (k == NBUCK - 1) ? 0xFFFFFFFFu : ((k + 1) << BSHIFT);
            double flo = (double)o2f(lou), fhi = (double)o2f(hiu);
            double fr = (e - flo) / (fhi - flo);
            fr = fr < 0.0 ? 0.0 : (fr > 1.0 ? 1.0 : fr);
            double cl = (double)excl[k], ch = (double)excl[k + 1];
            return cl + (ch - cl) * fr;
        };

        double c_hi = estcum(mn + (double)(t + 1) * delta);
        double c_lo = estcum(mn + (double)t * delta);
        if (c_hi > thr0 && !(c_lo > thr0)) out[0] = (float)(mn + (double)t * delta);
        if (c_hi > thr1 && !(c_lo > thr1)) out[1] = (float)(mn + (double)t * delta);
    }
}

extern "C" void kernel_launch(void* const* d_in, const int* in_sizes, int n_in,
                              void* d_out, int out_size, void* d_ws, size_t ws_size,
                              hipStream_t stream) {
    const float4* in = (const float4*)d_in[0];
    int n = in_sizes[0];
    int n16 = n / 16;
    unsigned int* wsu = (unsigned int*)d_ws;
    float* out = (float*)d_out;

    hrt_pass1<<<P1BLK, 256, 0, stream>>>(in, n16, wsu);
    hrt_reduce<<<256, 256, 0, stream>>>(wsu);
    hrt_finalize<<<1, 1024, 0, stream>>>(wsu, out);
}